// Round 1
// 2105.801 us; speedup vs baseline: 1.0475x; 1.0475x over previous
//
#include <hip/hip_runtime.h>
#include <stdint.h>
#include <stddef.h>

// FP8Linear == bias-GEMM: reference's block quant-dequant is an fp32 identity.
// Y[M,N] = X[M,K] @ W[N,K]^T + bias[N];  M=8192, N=16384, K=4096.
// Structure: 256x256 tile, BK=64, 8 waves (2Mx4N), 8-phase pipeline with
// counted vmcnt(6) (3 half-tiles in flight across barriers), XOR-swizzled
// LDS ((row&7)<<4 byte swizzle via pre-swizzled global source), setprio
// around MFMA clusters, bijective XCD-aware block swizzle.

typedef _Float16 f16_t;
typedef _Float16 f16x8 __attribute__((ext_vector_type(8)));
typedef float    f32x4 __attribute__((ext_vector_type(4)));

#define BM 256
#define BN 256
#define BK 64

// ---------------- fp32 -> fp16 conversion (8 elems/thread) ----------------
__global__ void __launch_bounds__(256) cvt_f32_to_f16(const float* __restrict__ src,
                                                      f16_t* __restrict__ dst,
                                                      int n8) {
    int i = blockIdx.x * 256 + threadIdx.x;
    if (i >= n8) return;
    const float4* s = (const float4*)src;
    float4 a = s[2 * i + 0];
    float4 b = s[2 * i + 1];
    f16x8 r;
    r[0] = (f16_t)a.x; r[1] = (f16_t)a.y; r[2] = (f16_t)a.z; r[3] = (f16_t)a.w;
    r[4] = (f16_t)b.x; r[5] = (f16_t)b.y; r[6] = (f16_t)b.z; r[7] = (f16_t)b.w;
    *(f16x8*)(dst + (size_t)i * 8) = r;
}

__device__ __forceinline__ void load_lds_16B(const f16_t* g, f16_t* l) {
    __builtin_amdgcn_global_load_lds(
        (const __attribute__((address_space(1))) void*)g,
        (__attribute__((address_space(3))) void*)l,
        16, 0, 0);
}

__global__ void __launch_bounds__(512, 2) gemm256_bias(const f16_t* __restrict__ A,
                                                       const f16_t* __restrict__ B,
                                                       const float* __restrict__ bias,
                                                       float* __restrict__ C,
                                                       int M, int N, int K) {
    // LDS: [buf2][half2] of 128x64 f16 per matrix: 64 KiB A + 64 KiB B.
    __shared__ __align__(16) f16_t sA[2 * 2 * 128 * 64];
    __shared__ __align__(16) f16_t sB[2 * 2 * 128 * 64];

    const int tid  = threadIdx.x;
    const int w    = tid >> 6;        // wave 0..7
    const int l    = tid & 63;
    const int wr   = w >> 2;          // 0..1 : wave row (128 rows each)
    const int wc   = w & 3;           // 0..3 : wave col (64 cols each)
    const int l16  = l & 15;
    const int quad = l >> 4;
    const int bh   = wc >> 1;         // which B half this wave reads
    const int brow = (wc & 1) * 64;   // row offset inside that half

    // fragment-read column offsets, swizzled: byte ^= (row&7)<<4, row&7 == l16&7
    const int sw    = (l16 & 7) << 4;
    const int coff0 = (quad * 16) ^ sw;
    const int coff1 = (quad * 16 + 64) ^ sw;

    // bijective XCD-aware block swizzle (m204)
    const int nwg = gridDim.x;
    const int q8  = nwg >> 3, r8 = nwg & 7;
    const int xcd = blockIdx.x & 7, off = blockIdx.x >> 3;
    const int swz = (xcd < r8 ? xcd * (q8 + 1) : r8 * (q8 + 1) + (xcd - r8) * q8) + off;
    const int MB  = M / BM;
    const int bm  = swz % MB;
    const int bn  = swz / MB;

    // staging: lane l, round j covers half-tile row R = j*64 + w*8 + (l>>3),
    // linear LDS pos (l&7)*16B holds swizzled col 16*((l&7)^(R&7)) -> pre-swizzle
    // the GLOBAL source so LDS ends up swizzled while global_load_lds writes linear.
    const int srow = w * 8 + (l >> 3);
    const int scol = 8 * ((l & 7) ^ ((l >> 3) & 7));
    const size_t stA = (size_t)(bm * BM + srow) * K + scol;
    const size_t stB = (size_t)(bn * BN + srow) * K + scol;
    f16_t* lwA = sA + w * 512;   // wave-uniform LDS base (+1024B per wave)
    f16_t* lwB = sB + w * 512;

#define STAGE_A(d, h, tt) do {                                                  \
        const f16_t* g_ = A + stA + (size_t)((h) * 128) * K + (size_t)(tt) * 64; \
        f16_t* l_ = lwA + ((d) * 2 + (h)) * 8192;                               \
        load_lds_16B(g_, l_);                                                   \
        load_lds_16B(g_ + (size_t)64 * K, l_ + 4096);                           \
    } while (0)
#define STAGE_B(d, h, tt) do {                                                  \
        const f16_t* g_ = B + stB + (size_t)((h) * 128) * K + (size_t)(tt) * 64; \
        f16_t* l_ = lwB + ((d) * 2 + (h)) * 8192;                               \
        load_lds_16B(g_, l_);                                                   \
        load_lds_16B(g_ + (size_t)64 * K, l_ + 4096);                           \
    } while (0)

    const char* rdA = (const char*)sA + wr * 16384;
    const char* rdB = (const char*)sB + bh * 16384 + brow * 128;

    f16x8 as[4][2];
    f16x8 b0[2][2], b1[2][2];
    f32x4 acc[8][4];
#pragma unroll
    for (int i = 0; i < 8; ++i)
#pragma unroll
        for (int j = 0; j < 4; ++j)
            acc[i][j] = (f32x4){0.f, 0.f, 0.f, 0.f};

#define LD_A(d, mibase) do { _Pragma("unroll")                                  \
        for (int i_ = 0; i_ < 4; ++i_) {                                        \
            const char* p_ = rdA + (d) * 32768 + (((mibase) + i_) * 16 + l16) * 128; \
            as[i_][0] = *(const f16x8*)(p_ + coff0);                            \
            as[i_][1] = *(const f16x8*)(p_ + coff1);                            \
        } } while (0)
#define LD_B(d, nibase, dst) do { _Pragma("unroll")                             \
        for (int n_ = 0; n_ < 2; ++n_) {                                        \
            const char* p_ = rdB + (d) * 32768 + (((nibase) + n_) * 16 + l16) * 128; \
            dst[n_][0] = *(const f16x8*)(p_ + coff0);                           \
            dst[n_][1] = *(const f16x8*)(p_ + coff1);                           \
        } } while (0)

#define MF(mibase, nibase, bset) do { _Pragma("unroll")                         \
        for (int i_ = 0; i_ < 4; ++i_) { _Pragma("unroll")                      \
            for (int n_ = 0; n_ < 2; ++n_) { _Pragma("unroll")                  \
                for (int k_ = 0; k_ < 2; ++k_)                                  \
                    acc[(mibase) + i_][(nibase) + n_] =                         \
                        __builtin_amdgcn_mfma_f32_16x16x32_f16(                 \
                            as[i_][k_], bset[n_][k_],                           \
                            acc[(mibase) + i_][(nibase) + n_], 0, 0, 0);        \
            } } } while (0)

#define WAIT_LGKM() do { asm volatile("s_waitcnt lgkmcnt(0)" ::: "memory");     \
        __builtin_amdgcn_sched_barrier(0); } while (0)
#define BAR() __builtin_amdgcn_s_barrier()

    const int KT  = K / BK;     // 64 K-tiles
    const int NIT = KT / 2;     // 2 tiles per iteration

    // prologue ledger (oldest->newest): B0(0) B1(0) A0(0) A1(0) B0(1) B1(1)
    STAGE_B(0, 0, 0); STAGE_B(0, 1, 0);
    STAGE_A(0, 0, 0); STAGE_A(0, 1, 0);
    STAGE_B(1, 0, 1); STAGE_B(1, 1, 1);

    for (int it = 0; it < NIT; ++it) {
        const int t01 = 2 * it + 1;
        int t23 = 2 * it + 2; if (t23 > KT - 1) t23 = KT - 1;   // clamped: keeps
        int t67 = 2 * it + 3; if (t67 > KT - 1) t67 = KT - 1;   // vmcnt ledger uniform

        // -- phase 0 (tile 2it, buf0, boundary) --
        STAGE_A(1, 0, t01);
        asm volatile("s_waitcnt vmcnt(6)" ::: "memory");  // 3 half-tiles stay in flight
        BAR();
        LD_A(0, 0); LD_B(0, 0, b0);
        WAIT_LGKM();
        __builtin_amdgcn_s_setprio(1);
        MF(0, 0, b0);
        __builtin_amdgcn_s_setprio(0);
        BAR();
        // -- phase 1 --
        LD_B(0, 2, b1);
        STAGE_A(1, 1, t01);
        BAR();
        WAIT_LGKM();
        __builtin_amdgcn_s_setprio(1);
        MF(0, 2, b1);
        __builtin_amdgcn_s_setprio(0);
        BAR();
        // -- phase 2 --
        LD_A(0, 4);
        STAGE_B(0, 0, t23);
        BAR();
        WAIT_LGKM();
        __builtin_amdgcn_s_setprio(1);
        MF(4, 0, b0);
        __builtin_amdgcn_s_setprio(0);
        BAR();
        // -- phase 3 --
        STAGE_B(0, 1, t23);
        BAR();
        __builtin_amdgcn_s_setprio(1);
        MF(4, 2, b1);
        __builtin_amdgcn_s_setprio(0);
        BAR();
        // -- phase 4 (tile 2it+1, buf1, boundary) --
        STAGE_A(0, 0, t23);
        asm volatile("s_waitcnt vmcnt(6)" ::: "memory");
        BAR();
        LD_A(1, 0); LD_B(1, 0, b0);
        WAIT_LGKM();
        __builtin_amdgcn_s_setprio(1);
        MF(0, 0, b0);
        __builtin_amdgcn_s_setprio(0);
        BAR();
        // -- phase 5 --
        LD_B(1, 2, b1);
        STAGE_A(0, 1, t23);
        BAR();
        WAIT_LGKM();
        __builtin_amdgcn_s_setprio(1);
        MF(0, 2, b1);
        __builtin_amdgcn_s_setprio(0);
        BAR();
        // -- phase 6 --
        LD_A(1, 4);
        STAGE_B(1, 0, t67);
        BAR();
        WAIT_LGKM();
        __builtin_amdgcn_s_setprio(1);
        MF(4, 0, b0);
        __builtin_amdgcn_s_setprio(0);
        BAR();
        // -- phase 7 --
        STAGE_B(1, 1, t67);
        BAR();
        __builtin_amdgcn_s_setprio(1);
        MF(4, 2, b1);
        __builtin_amdgcn_s_setprio(0);
        BAR();
    }

    asm volatile("s_waitcnt vmcnt(0)" ::: "memory");  // drain before endpgm

    // epilogue: C/D layout col = l16, row = quad*4 + r. Fuse bias.
    const int c0 = bn * BN + wc * 64;
    const int r0 = bm * BM + wr * 128;
#pragma unroll
    for (int ni = 0; ni < 4; ++ni) {
        const int col = c0 + ni * 16 + l16;
        const float bv = bias[col];
#pragma unroll
        for (int mi = 0; mi < 8; ++mi) {
            const int row0 = r0 + mi * 16 + quad * 4;
            float* cp = C + (size_t)row0 * N + col;
#pragma unroll
            for (int r = 0; r < 4; ++r)
                cp[(size_t)r * N] = acc[mi][ni][r] + bv;
        }
    }
}

extern "C" void kernel_launch(void* const* d_in, const int* in_sizes, int n_in,
                              void* d_out, int out_size, void* d_ws, size_t ws_size,
                              hipStream_t stream) {
    const float* X    = (const float*)d_in[0];   // [M,K]
    const float* W    = (const float*)d_in[1];   // [N,K]
    const float* bias = (const float*)d_in[2];   // [N]
    float* out        = (float*)d_out;           // [M,N]

    const int N = in_sizes[2];            // 16384
    const int K = in_sizes[1] / N;        // 4096
    const int M = in_sizes[0] / K;        // 8192

    f16_t* Xh = (f16_t*)d_ws;
    f16_t* Wh = Xh + (size_t)M * K;

    const int nx8 = (M * K) / 8;
    const int nw8 = (N * K) / 8;
    cvt_f32_to_f16<<<dim3((nx8 + 255) / 256), 256, 0, stream>>>(X, Xh, nx8);
    cvt_f32_to_f16<<<dim3((nw8 + 255) / 256), 256, 0, stream>>>(W, Wh, nw8);

    const int nblk = (M / BM) * (N / BN);  // 2048
    gemm256_bias<<<dim3(nblk), dim3(512), 0, stream>>>(Xh, Wh, bias, out, M, N, K);
}

// Round 2
// 1946.592 us; speedup vs baseline: 1.1332x; 1.0818x over previous
//
#include <hip/hip_runtime.h>
#include <stdint.h>
#include <stddef.h>

// FP8Linear == bias-GEMM: reference's block quant-dequant is an fp32 identity.
// Y[M,N] = X[M,K] @ W[N,K]^T + bias[N];  M=8192, N=16384, K=4096.
// 256x256 tile, BK=64, 8 waves (2Mx4N), 8-phase pipeline.
// Template-faithful m201 phase ordering: ds_reads issued at phase TOP
// (pre-barrier, overlapping barrier wait), lgkmcnt(0) after the barrier,
// counted vmcnt(4) at the END phase of each tile (phases 3/7) so the next
// buffer's reads can issue at the next phase top. XOR-swizzled LDS via
// pre-swizzled global source; setprio around MFMA; bijective XCD swizzle.

typedef _Float16 f16_t;
typedef _Float16 f16x8 __attribute__((ext_vector_type(8)));
typedef float    f32x4 __attribute__((ext_vector_type(4)));

#define BM 256
#define BN 256
#define BK 64

// ---------------- fp32 -> fp16 conversion (8 elems/thread) ----------------
__global__ void __launch_bounds__(256) cvt_f32_to_f16(const float* __restrict__ src,
                                                      f16_t* __restrict__ dst,
                                                      int n8) {
    int i = blockIdx.x * 256 + threadIdx.x;
    if (i >= n8) return;
    const float4* s = (const float4*)src;
    float4 a = s[2 * i + 0];
    float4 b = s[2 * i + 1];
    f16x8 r;
    r[0] = (f16_t)a.x; r[1] = (f16_t)a.y; r[2] = (f16_t)a.z; r[3] = (f16_t)a.w;
    r[4] = (f16_t)b.x; r[5] = (f16_t)b.y; r[6] = (f16_t)b.z; r[7] = (f16_t)b.w;
    *(f16x8*)(dst + (size_t)i * 8) = r;
}

__device__ __forceinline__ void load_lds_16B(const f16_t* g, f16_t* l) {
    __builtin_amdgcn_global_load_lds(
        (const __attribute__((address_space(1))) void*)g,
        (__attribute__((address_space(3))) void*)l,
        16, 0, 0);
}

__global__ void __launch_bounds__(512, 2) gemm256_bias(const f16_t* __restrict__ A,
                                                       const f16_t* __restrict__ B,
                                                       const float* __restrict__ bias,
                                                       float* __restrict__ C,
                                                       int M, int N, int K) {
    // LDS: [buf2][half2] of 128x64 f16 per matrix: 64 KiB A + 64 KiB B.
    __shared__ __align__(16) f16_t sA[2 * 2 * 128 * 64];
    __shared__ __align__(16) f16_t sB[2 * 2 * 128 * 64];

    const int tid  = threadIdx.x;
    const int w    = tid >> 6;        // wave 0..7
    const int l    = tid & 63;
    const int wr   = w >> 2;          // 0..1 : wave row (128 rows each)
    const int wc   = w & 3;           // 0..3 : wave col (64 cols each)
    const int l16  = l & 15;
    const int quad = l >> 4;
    const int bh   = wc >> 1;         // which B half this wave reads
    const int brow = (wc & 1) * 64;   // row offset inside that half

    // fragment-read column offsets, swizzled: byte ^= (row&7)<<4, row&7 == l16&7
    const int sw    = (l16 & 7) << 4;
    const int coff0 = (quad * 16) ^ sw;
    const int coff1 = (quad * 16 + 64) ^ sw;

    // bijective XCD-aware block swizzle (m204)
    const int nwg = gridDim.x;
    const int q8  = nwg >> 3, r8 = nwg & 7;
    const int xcd = blockIdx.x & 7, off = blockIdx.x >> 3;
    const int swz = (xcd < r8 ? xcd * (q8 + 1) : r8 * (q8 + 1) + (xcd - r8) * q8) + off;
    const int MB  = M / BM;
    const int bm  = swz % MB;
    const int bn  = swz / MB;

    // staging: lane l, round j covers half-tile row R = j*64 + w*8 + (l>>3),
    // linear LDS pos (l&7)*16B holds swizzled col 16*((l&7)^(R&7)) -> pre-swizzle
    // the GLOBAL source so LDS ends up swizzled while global_load_lds writes linear.
    const int srow = w * 8 + (l >> 3);
    const int scol = 8 * ((l & 7) ^ ((l >> 3) & 7));
    const size_t stA = (size_t)(bm * BM + srow) * K + scol;
    const size_t stB = (size_t)(bn * BN + srow) * K + scol;
    f16_t* lwA = sA + w * 512;   // wave-uniform LDS base (+1024B per wave)
    f16_t* lwB = sB + w * 512;

#define STAGE_A(d, h, tt) do {                                                  \
        const f16_t* g_ = A + stA + (size_t)((h) * 128) * K + (size_t)(tt) * 64; \
        f16_t* l_ = lwA + ((d) * 2 + (h)) * 8192;                               \
        load_lds_16B(g_, l_);                                                   \
        load_lds_16B(g_ + (size_t)64 * K, l_ + 4096);                           \
    } while (0)
#define STAGE_B(d, h, tt) do {                                                  \
        const f16_t* g_ = B + stB + (size_t)((h) * 128) * K + (size_t)(tt) * 64; \
        f16_t* l_ = lwB + ((d) * 2 + (h)) * 8192;                               \
        load_lds_16B(g_, l_);                                                   \
        load_lds_16B(g_ + (size_t)64 * K, l_ + 4096);                           \
    } while (0)

    const char* rdA = (const char*)sA + wr * 16384;
    const char* rdB = (const char*)sB + bh * 16384 + brow * 128;

    f16x8 as[4][2];
    f16x8 b0[2][2], b1[2][2];
    f32x4 acc[8][4];
#pragma unroll
    for (int i = 0; i < 8; ++i)
#pragma unroll
        for (int j = 0; j < 4; ++j)
            acc[i][j] = (f32x4){0.f, 0.f, 0.f, 0.f};

#define LD_A(d, mibase) do { _Pragma("unroll")                                  \
        for (int i_ = 0; i_ < 4; ++i_) {                                        \
            const char* p_ = rdA + (d) * 32768 + (((mibase) + i_) * 16 + l16) * 128; \
            as[i_][0] = *(const f16x8*)(p_ + coff0);                            \
            as[i_][1] = *(const f16x8*)(p_ + coff1);                            \
        } } while (0)
#define LD_B(d, nibase, dst) do { _Pragma("unroll")                             \
        for (int n_ = 0; n_ < 2; ++n_) {                                        \
            const char* p_ = rdB + (d) * 32768 + (((nibase) + n_) * 16 + l16) * 128; \
            dst[n_][0] = *(const f16x8*)(p_ + coff0);                           \
            dst[n_][1] = *(const f16x8*)(p_ + coff1);                           \
        } } while (0)

#define MF(mibase, nibase, bset) do { _Pragma("unroll")                         \
        for (int i_ = 0; i_ < 4; ++i_) { _Pragma("unroll")                      \
            for (int n_ = 0; n_ < 2; ++n_) { _Pragma("unroll")                  \
                for (int k_ = 0; k_ < 2; ++k_)                                  \
                    acc[(mibase) + i_][(nibase) + n_] =                         \
                        __builtin_amdgcn_mfma_f32_16x16x32_f16(                 \
                            as[i_][k_], bset[n_][k_],                           \
                            acc[(mibase) + i_][(nibase) + n_], 0, 0, 0);        \
            } } } while (0)

#define WAIT_LGKM() do { asm volatile("s_waitcnt lgkmcnt(0)" ::: "memory");     \
        __builtin_amdgcn_sched_barrier(0); } while (0)
#define BAR() __builtin_amdgcn_s_barrier()
#define PRIO_MF(mi, ni, bs) do { __builtin_amdgcn_s_setprio(1);                 \
        MF(mi, ni, bs); __builtin_amdgcn_s_setprio(0); } while (0)

    const int KT  = K / BK;     // 64 K-tiles
    const int NIT = KT / 2;     // 2 tiles per iteration

    // prologue ledger (oldest->newest): B0(0) B1(0) A0(0) A1(0) | B0(1) B1(1)
    STAGE_B(0, 0, 0); STAGE_B(0, 1, 0);
    STAGE_A(0, 0, 0); STAGE_A(0, 1, 0);
    STAGE_B(1, 0, 1); STAGE_B(1, 1, 1);
    asm volatile("s_waitcnt vmcnt(4)" ::: "memory");  // buf0 complete; B(1,*) in flight
    BAR();

    for (int it = 0; it < NIT; ++it) {
        const int tU = 2 * it + 1;
        int tV = 2 * it + 2; if (tV > KT - 1) tV = KT - 1;   // clamped: keeps
        int tW = 2 * it + 3; if (tW > KT - 1) tW = KT - 1;   // vmcnt ledger uniform

        // -- ph0: buf0 Q(0..3, 0..1). reads issue pre-barrier; stage A of tile U.
        LD_A(0, 0); LD_B(0, 0, b0);
        STAGE_A(1, 0, tU); STAGE_A(1, 1, tU);
        BAR();
        WAIT_LGKM();
        PRIO_MF(0, 0, b0);
        BAR();
        // -- ph1: Q(0..3, 2..3)
        LD_B(0, 2, b1);
        BAR();
        WAIT_LGKM();
        PRIO_MF(0, 2, b1);
        BAR();
        // -- ph2: Q(4..7, 0..1); stage B of tile V (buf0-B last read was ph1)
        LD_A(0, 4);
        STAGE_B(0, 0, tV); STAGE_B(0, 1, tV);
        BAR();
        WAIT_LGKM();
        PRIO_MF(4, 0, b0);
        BAR();
        // -- ph3: Q(4..7, 2..3); vmcnt(4) publishes buf1 (tile U) for ph4 reads
        asm volatile("s_waitcnt vmcnt(4)" ::: "memory");
        BAR();
        PRIO_MF(4, 2, b1);
        BAR();
        // -- ph4: buf1 Q(0..3, 0..1); stage A of tile V (buf0-A last read ph2)
        LD_A(1, 0); LD_B(1, 0, b0);
        STAGE_A(0, 0, tV); STAGE_A(0, 1, tV);
        BAR();
        WAIT_LGKM();
        PRIO_MF(0, 0, b0);
        BAR();
        // -- ph5
        LD_B(1, 2, b1);
        BAR();
        WAIT_LGKM();
        PRIO_MF(0, 2, b1);
        BAR();
        // -- ph6: stage B of tile W (buf1-B last read ph5)
        LD_A(1, 4);
        STAGE_B(1, 0, tW); STAGE_B(1, 1, tW);
        BAR();
        WAIT_LGKM();
        PRIO_MF(4, 0, b0);
        BAR();
        // -- ph7: vmcnt(4) publishes buf0 (tile V) for next ph0 reads
        asm volatile("s_waitcnt vmcnt(4)" ::: "memory");
        BAR();
        PRIO_MF(4, 2, b1);
        BAR();
    }

    asm volatile("s_waitcnt vmcnt(0)" ::: "memory");  // drain tail stages

    // epilogue: C/D layout col = l16, row = quad*4 + r. Fuse bias.
    const int c0 = bn * BN + wc * 64;
    const int r0 = bm * BM + wr * 128;
#pragma unroll
    for (int ni = 0; ni < 4; ++ni) {
        const int col = c0 + ni * 16 + l16;
        const float bv = bias[col];
#pragma unroll
        for (int mi = 0; mi < 8; ++mi) {
            const int row0 = r0 + mi * 16 + quad * 4;
            float* cp = C + (size_t)row0 * N + col;
#pragma unroll
            for (int r = 0; r < 4; ++r)
                cp[(size_t)r * N] = acc[mi][ni][r] + bv;
        }
    }
}

extern "C" void kernel_launch(void* const* d_in, const int* in_sizes, int n_in,
                              void* d_out, int out_size, void* d_ws, size_t ws_size,
                              hipStream_t stream) {
    const float* X    = (const float*)d_in[0];   // [M,K]
    const float* W    = (const float*)d_in[1];   // [N,K]
    const float* bias = (const float*)d_in[2];   // [N]
    float* out        = (float*)d_out;           // [M,N]

    const int N = in_sizes[2];            // 16384
    const int K = in_sizes[1] / N;        // 4096
    const int M = in_sizes[0] / K;        // 8192

    f16_t* Xh = (f16_t*)d_ws;
    f16_t* Wh = Xh + (size_t)M * K;

    const int nx8 = (M * K) / 8;
    const int nw8 = (N * K) / 8;
    cvt_f32_to_f16<<<dim3((nx8 + 255) / 256), 256, 0, stream>>>(X, Xh, nx8);
    cvt_f32_to_f16<<<dim3((nw8 + 255) / 256), 256, 0, stream>>>(W, Wh, nw8);

    const int nblk = (M / BM) * (N / BN);  // 2048
    gemm256_bias<<<dim3(nblk), dim3(512), 0, stream>>>(Xh, Wh, bias, out, M, N, K);
}